// Round 1
// baseline (169.681 us; speedup 1.0000x reference)
//
#include <hip/hip_runtime.h>

#define HH 256
#define WW 256
#define CC 32
#define HWSZ (HH * WW)
#define IMGSZ (CC * HWSZ)
#define NIMG 8
#define EPSV 1e-8f

// Load the 3x6 halo of values for one channel around this thread's 4 pixels.
// v[r][j] = F[c, y+r-1, x0+j-1], zero outside the image.
__device__ __forceinline__ void load_halo(const float* __restrict__ plane,
                                          const bool* rowok, bool xl, bool xr,
                                          float v[3][6])
{
#pragma unroll
    for (int r = 0; r < 3; ++r) {
        const float* row = plane + (r - 1) * WW;
        if (rowok[r]) {
            float4 m = *reinterpret_cast<const float4*>(row);
            v[r][1] = m.x; v[r][2] = m.y; v[r][3] = m.z; v[r][4] = m.w;
            v[r][0] = xl ? row[-1] : 0.f;
            v[r][5] = xr ? row[4]  : 0.f;
        } else {
#pragma unroll
            for (int j = 0; j < 6; ++j) v[r][j] = 0.f;
        }
    }
}

// One "step": given features F (per image, CxHxW), write the total-sim map
// (per image HxW) and, if COMPUTE_NEXT, the softmax-neighbor-averaged F_next.
template <bool COMPUTE_NEXT>
__global__ __launch_bounds__(256) void step_kernel(const float* __restrict__ F,
                                                   float* __restrict__ Fn,
                                                   float* __restrict__ simout)
{
    const int tx = threadIdx.x & 63;   // 64 threads across x, 4 px each = 256
    const int ty = threadIdx.x >> 6;   // 4 rows per block
    const int y  = (blockIdx.x << 2) + ty;
    const int b  = blockIdx.y;
    const int x0 = tx << 2;

    const float* Fb = F + (size_t)b * IMGSZ;
    const bool ym = y > 0, yp = y < HH - 1;
    const bool xl = x0 > 0, xr = x0 < WW - 4;
    const bool rowok[3] = { ym, true, yp };
    const bool colok[6] = { xl, true, true, true, true, xr };

    // Accumulators: squares at all 18 halo positions (gives self + neighbor
    // norms), and 8 neighbor dot products for each of the 4 center pixels.
    float sq[3][6];
    float dotv[8][4];
#pragma unroll
    for (int r = 0; r < 3; ++r)
#pragma unroll
        for (int j = 0; j < 6; ++j) sq[r][j] = 0.f;
#pragma unroll
    for (int d = 0; d < 8; ++d)
#pragma unroll
        for (int i = 0; i < 4; ++i) dotv[d][i] = 0.f;

    for (int c = 0; c < CC; ++c) {
        const float* plane = Fb + c * HWSZ + y * WW + x0;
        float v[3][6];
        load_halo(plane, rowok, xl, xr, v);
#pragma unroll
        for (int r = 0; r < 3; ++r)
#pragma unroll
            for (int j = 0; j < 6; ++j) sq[r][j] = fmaf(v[r][j], v[r][j], sq[r][j]);
        int d = 0;
#pragma unroll
        for (int dyi = 0; dyi < 3; ++dyi)
#pragma unroll
            for (int dxi = 0; dxi < 3; ++dxi) {
                if (dyi == 1 && dxi == 1) continue;
#pragma unroll
                for (int i = 0; i < 4; ++i)
                    dotv[d][i] = fmaf(v[1][i + 1], v[dyi][i + dxi], dotv[d][i]);
                ++d;
            }
    }

    float nrm[3][6];
#pragma unroll
    for (int r = 0; r < 3; ++r)
#pragma unroll
        for (int j = 0; j < 6; ++j) nrm[r][j] = sqrtf(sq[r][j]);

    float w[8][4];      // softmax weights (only used when COMPUTE_NEXT)
    float simarr[4];
#pragma unroll
    for (int i = 0; i < 4; ++i) {
        float s[8];
        const float cn = nrm[1][i + 1];
        float tot = 0.f, cnt = 0.f;
        int d = 0;
#pragma unroll
        for (int dyi = 0; dyi < 3; ++dyi)
#pragma unroll
            for (int dxi = 0; dxi < 3; ++dxi) {
                if (dyi == 1 && dxi == 1) continue;
                const bool m = rowok[dyi] && colok[i + dxi];
                const float den = fmaxf(cn * nrm[dyi][i + dxi], EPSV);
                const float cs = dotv[d][i] / den;
                s[d] = m ? cs : 0.f;
                tot += s[d];
                cnt += m ? 1.f : 0.f;
                ++d;
            }
        simarr[i] = tot / cnt;
        if (COMPUTE_NEXT) {
            float mx = s[0];
#pragma unroll
            for (int d2 = 1; d2 < 8; ++d2) mx = fmaxf(mx, s[d2]);
            float wsum = 0.f;
#pragma unroll
            for (int d2 = 0; d2 < 8; ++d2) { w[d2][i] = __expf(s[d2] - mx); wsum += w[d2][i]; }
            const float inv = 1.f / wsum;
#pragma unroll
            for (int d2 = 0; d2 < 8; ++d2) w[d2][i] *= inv;
        }
    }
    float4 simv = { simarr[0], simarr[1], simarr[2], simarr[3] };
    *reinterpret_cast<float4*>(simout + b * HWSZ + y * WW + x0) = simv;

    if (COMPUTE_NEXT) {
        // Second channel pass: weighted neighbor average (re-reads are L1/L2 hot).
        for (int c = 0; c < CC; ++c) {
            const float* plane = Fb + c * HWSZ + y * WW + x0;
            float v[3][6];
            load_halo(plane, rowok, xl, xr, v);
            float o[4] = { 0.f, 0.f, 0.f, 0.f };
            int d = 0;
#pragma unroll
            for (int dyi = 0; dyi < 3; ++dyi)
#pragma unroll
                for (int dxi = 0; dxi < 3; ++dxi) {
                    if (dyi == 1 && dxi == 1) continue;
#pragma unroll
                    for (int i = 0; i < 4; ++i)
                        o[i] = fmaf(w[d][i], v[dyi][i + dxi], o[i]);
                    ++d;
                }
            float4 ov = { o[0], o[1], o[2], o[3] };
            *reinterpret_cast<float4*>(Fn + (size_t)b * IMGSZ + c * HWSZ + y * WW + x0) = ov;
        }
    }
}

// out[g][t][p] = 0.25 * sum_{i<4} sims[tt][4g+i][p], tt = {0,0,1,2}[t]
__global__ __launch_bounds__(256) void reduce_kernel(const float* __restrict__ sims,
                                                     float* __restrict__ out)
{
    const int idx = blockIdx.x * blockDim.x + threadIdx.x;  // 131072 float4s
    const int p4 = idx & (HWSZ / 4 - 1);
    const int t  = (idx >> 14) & 3;
    const int g  = idx >> 16;
    const int tt = (t <= 1) ? 0 : (t - 1);
    const float4* s = reinterpret_cast<const float4*>(sims) +
                      (size_t)(tt * NIMG + g * 4) * (HWSZ / 4) + p4;
    float4 a = s[0];
    float4 b = s[HWSZ / 4];
    float4 c = s[2 * (HWSZ / 4)];
    float4 d = s[3 * (HWSZ / 4)];
    float4 o;
    o.x = 0.25f * (a.x + b.x + c.x + d.x);
    o.y = 0.25f * (a.y + b.y + c.y + d.y);
    o.z = 0.25f * (a.z + b.z + c.z + d.z);
    o.w = 0.25f * (a.w + b.w + c.w + d.w);
    reinterpret_cast<float4*>(out)[idx] = o;
}

extern "C" void kernel_launch(void* const* d_in, const int* in_sizes, int n_in,
                              void* d_out, int out_size, void* d_ws, size_t ws_size,
                              hipStream_t stream)
{
    const float* F0 = (const float*)d_in[0];
    float* F1   = (float*)d_ws;                       // 8*IMGSZ floats (64 MB)
    float* F2   = F1 + (size_t)NIMG * IMGSZ;          // 64 MB
    float* sims = F2 + (size_t)NIMG * IMGSZ;          // 3 * 8 * HWSZ floats (6 MB)

    dim3 block(256);
    dim3 grid(HH / 4, NIMG);

    hipLaunchKernelGGL((step_kernel<true>),  grid, block, 0, stream, F0, F1, sims);
    hipLaunchKernelGGL((step_kernel<true>),  grid, block, 0, stream, F1, F2, sims + (size_t)NIMG * HWSZ);
    hipLaunchKernelGGL((step_kernel<false>), grid, block, 0, stream, F2, nullptr, sims + (size_t)2 * NIMG * HWSZ);

    hipLaunchKernelGGL(reduce_kernel, dim3((2 * 4 * HWSZ / 4) / 256), block, 0, stream,
                       sims, (float*)d_out);
}